// Round 10
// baseline (453.673 us; speedup 1.0000x reference)
//
#include <hip/hip_runtime.h>

#define LMAX   10
#define BATCH  16384
#define NCOLS  381
#define NF     121
#define NPAIRS 66

typedef __attribute__((ext_vector_type(8))) short    short8;
typedef __attribute__((ext_vector_type(8))) _Float16 half8;
typedef __attribute__((ext_vector_type(2))) _Float16 half2v;
typedef __attribute__((ext_vector_type(4))) float    floatx4;

__device__ __forceinline__ short f32_to_f16_bits(float x) {
    return __builtin_bit_cast(short, (_Float16)x);   // RNE
}

// pair index p -> (l1, l2, cg offset, first output column, cg16 offset)
__device__ __forceinline__ void decode_pair_ext(int p, int& l1, int& l2,
                                                long long& off, int& colbase,
                                                int& c16off)
{
    long long o = 0; int cb = 0, c16 = 0, idx = 0;
    for (int a = 0; a <= LMAX; ++a) {
        for (int bq = a; bq <= LMAX; ++bq) {
            const int d    = (2*a+1)*(2*bq+1);
            const int lmin = bq - a;
            const int lmx  = (a + bq < LMAX) ? (a + bq) : LMAX;
            const int used = (lmx+1)*(lmx+1) - lmin*lmin;
            const int npan = (d + 31) >> 5;
            const int nt   = (used + 15) >> 4;
            if (idx == p) { l1 = a; l2 = bq; off = o; colbase = cb; c16off = c16; return; }
            o += (long long)d * d; cb += lmx - lmin + 1;
            c16 += nt * 16 * npan * 32; ++idx;
        }
    }
    l1 = l2 = 0; off = 0; colbase = 0; c16off = 0;
}

// ---------------------------------------------------------------------------
// Kernel 1: expand coeffs into f planes, layout (121, BATCH) float2 (fp32).
// Verified (rounds 3/5/7/8).
// ---------------------------------------------------------------------------
__global__ __launch_bounds__(256) void build_f(const float* __restrict__ cre,
                                               const float* __restrict__ cim,
                                               float2* __restrict__ f)
{
    const int b   = blockIdx.x * blockDim.x + threadIdx.x;
    const int idx = blockIdx.y;                              // 0..120
    int l = (int)sqrtf((float)idx + 0.5f);
    if (l * l > idx) --l;
    if ((l + 1) * (l + 1) <= idx) ++l;
    const int j = idx - l * l;
    const int m = j - l;
    const float* crow  = cre + (size_t)b * 121 + l * 11;
    const float* cirow = cim + (size_t)b * 121 + l * 11;
    float re, im;
    if (m >= 0) { re = crow[m]; im = cirow[m]; }
    else {
        const int a = -m;
        const float sg = (a & 1) ? -1.0f : 1.0f;
        re = sg * crow[a]; im = -sg * cirow[a];
    }
    f[(size_t)idx * BATCH + b] = make_float2(re, im);
}

// ---------------------------------------------------------------------------
// Kernel 2: cg (fp32, [k][n] per pair) -> cg16 (f16, transposed [n][k],
// zero-padded to [nt*16][npan*32]). Verified (rounds 7/8).
// ---------------------------------------------------------------------------
__global__ __launch_bounds__(256) void cg_to_f16(const float* __restrict__ cg,
                                                 short* __restrict__ cg16)
{
    int l1, l2, colbase, c16off; long long off;
    decode_pair_ext(blockIdx.y, l1, l2, off, colbase, c16off);
    const int d    = (2*l1+1)*(2*l2+1);
    const int lmin = l2 - l1;
    const int lmx  = (l1 + l2 < LMAX) ? (l1 + l2) : LMAX;
    const int used = (lmx+1)*(lmx+1) - lmin*lmin;
    const int npan = (d + 31) >> 5;
    const int nt   = (used + 15) >> 4;
    const int K32  = npan * 32;
    const int kbase = blockIdx.x * 64;
    if (kbase >= K32) return;
    const int kend  = (kbase + 64 < K32) ? kbase + 64 : K32;
    const int usedp = nt * 16;
    const int nn = threadIdx.x & 127;
    const int kh = threadIdx.x >> 7;
    if (nn >= usedp) return;
    for (int k = kbase + kh; k < kend; k += 2) {
        float v = 0.f;
        if (nn < used && k < d)
            v = cg[off + (size_t)k * d + nn];
        cg16[(size_t)c16off + (size_t)nn * K32 + k] = f32_to_f16_bits(v);
    }
}

// ---------------------------------------------------------------------------
// MFMA pair kernel, barrier-free K-loop (round 9) + T-store bounds guard:
//  - f1/f2 cached once in LDS (f12[m][65] packed half2, padded stride).
//  - A fragments computed per-lane in registers.
//  - B fragments loaded per-wave directly from global cg16 (L1/L2-hot).
//  - NO __syncthreads inside the K-loop.
//  - T[64][123]: stores guarded col<123 — cols 123..127 are provably zero
//    (cg16 zero-padding) and never read (max read col = used-1 <= 120).
// LDS: union{ f12 (<=10.9 KB), T[64][123] fp32 (31.5 KB) } -> 31.5 KB.
// ---------------------------------------------------------------------------
template<int NT>
__device__ __forceinline__ void pair_body(const float2* __restrict__ f,
                                          const short* __restrict__ cg16,
                                          float* __restrict__ out,
                                          short* smem, int btile,
                                          int l1, int l2, int c16off, int colbase)
{
    const int d1 = 2*l1 + 1, d2 = 2*l2 + 1, d = d1 * d2;
    const int lmin = l2 - l1;
    const int lmx  = (l1 + l2 < LMAX) ? (l1 + l2) : LMAX;
    const int n_l  = lmx - lmin + 1;
    const int q1 = l1*l1, q2 = l2*l2;
    const int npan = (d + 31) >> 5;
    const int K32  = npan * 32;

    const int tid  = threadIdx.x;
    const int lane = tid & 63;
    const int w    = tid >> 6;        // wave 0..3 -> M-tile
    const int quad = lane >> 4;
    const int r16  = lane & 15;

    unsigned int* f12 = (unsigned int*)smem;   // [m][65] packed half2

    // ---- load f1/f2 batch-tiles once, packed half2 {re, im} ----
    {
        const int nmm = (d1 + d2) * 64;
        for (int t2 = tid; t2 < nmm; t2 += 256) {
            const int m   = t2 >> 6;
            const int row = t2 & 63;
            const float2 v = (m < d1)
                ? f[(size_t)(q1 + m)      * BATCH + btile + row]
                : f[(size_t)(q2 + m - d1) * BATCH + btile + row];
            half2v h; h.x = (_Float16)v.x; h.y = (_Float16)v.y;
            f12[m * 65 + row] = __builtin_bit_cast(unsigned int, h);
        }
    }
    __syncthreads();

    floatx4 accR[NT], accI[NT];
#pragma unroll
    for (int i = 0; i < NT; ++i) {
        accR[i] = (floatx4)0.0f; accI[i] = (floatx4)0.0f;
    }

    const int row = w * 16 + r16;                 // this lane's batch row
    const short* cgbase = cg16 + (size_t)c16off;

    for (int pan = 0; pan < npan; ++pan) {
        const int k0 = pan << 5;

        // ---- A fragment in registers: tp[row][k0+quad*8 .. +7] (f16) ----
        int kk = k0 + quad * 8;
        int m1 = kk / d2;
        int m2 = kk - m1 * d2;
        short8 vr, vi;
#pragma unroll
        for (int j = 0; j < 8; ++j) {
            _Float16 tr = (_Float16)0.f, ti = (_Float16)0.f;
            if (kk < d) {
                const half2v a = __builtin_bit_cast(half2v, f12[m1 * 65 + row]);
                const half2v c = __builtin_bit_cast(half2v, f12[(d1 + m2) * 65 + row]);
                tr = a.x * c.x - a.y * c.y;
                ti = a.x * c.y + a.y * c.x;
            }
            vr[j] = __builtin_bit_cast(short, tr);
            vi[j] = __builtin_bit_cast(short, ti);
            ++kk;
            if (++m2 == d2) { m2 = 0; ++m1; }
        }
        const half8 are = __builtin_bit_cast(half8, vr);
        const half8 aim = __builtin_bit_cast(half8, vi);

        // ---- B fragments straight from global (L1/L2-hot), then MFMA ----
#pragma unroll
        for (int n0 = 0; n0 < NT; ++n0) {
            const short8 b16 = *(const short8*)(cgbase
                               + (size_t)(n0 * 16 + r16) * K32 + k0 + quad * 8);
            const half8 bb = __builtin_bit_cast(half8, b16);
            accR[n0] = __builtin_amdgcn_mfma_f32_16x16x32_f16(are, bb, accR[n0], 0, 0, 0);
            accI[n0] = __builtin_amdgcn_mfma_f32_16x16x32_f16(aim, bb, accI[n0], 0, 0, 0);
        }
    }
    __syncthreads();   // f12 dead; T may now overwrite LDS

    // ---- two-pass fp32 epilogue; C/D: col=lane&15, row=quad*4+reg ----
    float* T = (float*)smem;                  // [64][123] fp32
    const int ntask = 64 * n_l;
    float part[3] = {0.f, 0.f, 0.f};

    // pass 1: real
#pragma unroll
    for (int n0 = 0; n0 < NT; ++n0)
#pragma unroll
        for (int r = 0; r < 4; ++r) {
            const int col = n0*16 + r16;
            if (col < 123)
                T[(w*16 + quad*4 + r) * 123 + col] = accR[n0][r];
        }
    __syncthreads();
    {
        int it = 0;
        for (int task = tid; task < ntask; task += 256, ++it) {
            const int trow = task & 63;
            const int li   = task >> 6;
            const int l    = lmin + li;
            const int sl   = l*l - lmin*lmin;
            const int W    = 2*l + 1;
            const int b    = btile + trow;
            const float* Trow = T + trow * 123 + sl;
            float acc = 0.f;
            for (int j = 0; j < W; ++j)
                acc = fmaf(Trow[j], f[(size_t)(l*l + j) * BATCH + b].x, acc);
            part[it] = acc;
        }
    }
    __syncthreads();

    // pass 2: imaginary
#pragma unroll
    for (int n0 = 0; n0 < NT; ++n0)
#pragma unroll
        for (int r = 0; r < 4; ++r) {
            const int col = n0*16 + r16;
            if (col < 123)
                T[(w*16 + quad*4 + r) * 123 + col] = accI[n0][r];
        }
    __syncthreads();
    {
        int it = 0;
        for (int task = tid; task < ntask; task += 256, ++it) {
            const int trow = task & 63;
            const int li   = task >> 6;
            const int l    = lmin + li;
            const int sl   = l*l - lmin*lmin;
            const int W    = 2*l + 1;
            const int b    = btile + trow;
            const float* Trow = T + trow * 123 + sl;
            float acc = part[it];
            for (int j = 0; j < W; ++j)
                acc = fmaf(Trow[j], f[(size_t)(l*l + j) * BATCH + b].y, acc);
            out[(size_t)b * NCOLS + colbase + li] = acc;
        }
    }
}

__global__ __launch_bounds__(256, 4) void so3_mfma(const float2* __restrict__ f,
                                                   const short* __restrict__ cg16,
                                                   float* __restrict__ out)
{
    __shared__ __align__(16) short smem[15744];   // 31.5 KB (T[64][123] fp32)
    const int btile = blockIdx.x * 64;
    const int p     = blockIdx.y;
    int l1, l2, colbase, c16off; long long off;
    decode_pair_ext(p, l1, l2, off, colbase, c16off);
    const int lmin = l2 - l1;
    const int lmx  = (l1 + l2 < LMAX) ? (l1 + l2) : LMAX;
    const int used = (lmx+1)*(lmx+1) - lmin*lmin;
    const int nt   = (used + 15) >> 4;
    switch (nt) {
        case 1: pair_body<1>(f, cg16, out, smem, btile, l1, l2, c16off, colbase); break;
        case 2: pair_body<2>(f, cg16, out, smem, btile, l1, l2, c16off, colbase); break;
        case 3: pair_body<3>(f, cg16, out, smem, btile, l1, l2, c16off, colbase); break;
        case 4: pair_body<4>(f, cg16, out, smem, btile, l1, l2, c16off, colbase); break;
        case 5: pair_body<5>(f, cg16, out, smem, btile, l1, l2, c16off, colbase); break;
        case 6: pair_body<6>(f, cg16, out, smem, btile, l1, l2, c16off, colbase); break;
        case 7: pair_body<7>(f, cg16, out, smem, btile, l1, l2, c16off, colbase); break;
        default: pair_body<8>(f, cg16, out, smem, btile, l1, l2, c16off, colbase); break;
    }
}

// ---------------------------------------------------------------------------
// Full fallback (fp32 VALU, no workspace). Round-5 copy.
// ---------------------------------------------------------------------------
template<int L>
__device__ __forceinline__ float core_fb(const float2* f1v, const float2* f2v,
                                         const float2* flv,
                                         const float* __restrict__ cgp,
                                         int d1, int d2, int d)
{
    constexpr int W = 2*L + 1;
    float accr[W], acci[W];
#pragma unroll
    for (int k = 0; k < W; ++k) { accr[k] = 0.f; acci[k] = 0.f; }
    for (int m1 = 0; m1 < d1; ++m1) {
        const float2 a = f1v[m1];
        const float* rowbase = cgp + (size_t)m1 * d2 * d;
        for (int m2 = 0; m2 < d2; ++m2) {
            const float2 bb = f2v[m2];
            const float tr = a.x*bb.x - a.y*bb.y;
            const float ti = a.x*bb.y + a.y*bb.x;
            const float* row = rowbase + (size_t)m2 * d;
#pragma unroll
            for (int k = 0; k < W; ++k) {
                accr[k] = fmaf(tr, row[k], accr[k]);
                acci[k] = fmaf(ti, row[k], acci[k]);
            }
        }
    }
    float orr = 0.f;
#pragma unroll
    for (int k = 0; k < W; ++k)
        orr = fmaf(accr[k], flv[k].x, fmaf(acci[k], flv[k].y, orr));
    return orr;
}

__global__ __launch_bounds__(256) void so3_tp_direct(const float* __restrict__ cre,
                                                     const float* __restrict__ cim,
                                                     const float* __restrict__ cg,
                                                     float* __restrict__ out)
{
    const int b = blockIdx.x * blockDim.x + threadIdx.x;
    const int t = blockIdx.y;
    int l1 = 0, l2 = 0, l = 0; long long off = 0;
    {
        int tt = t; long long o = 0;
        bool found = false;
        for (int a = 0; a <= LMAX && !found; ++a)
            for (int bq = a; bq <= LMAX && !found; ++bq) {
                const int d = (2*a+1)*(2*bq+1);
                const int lmin = bq - a;
                const int lmx = (a+bq < LMAX) ? (a+bq) : LMAX;
                const int cnt = lmx - lmin + 1;
                if (tt < cnt) { l1 = a; l2 = bq; l = lmin + tt; off = o; found = true; }
                else { tt -= cnt; o += (long long)d*d; }
            }
    }
    const int d1 = 2*l1+1, d2 = 2*l2+1, d = d1*d2;
    const int lmin = l2 - l1;
    const int s = l*l - lmin*lmin;

    const float* cr = cre + (size_t)b * 121;
    const float* ci = cim + (size_t)b * 121;
    float2 f1v[21], f2v[21], flv[21];
    for (int j = 0; j <= 2*l1; ++j) {
        const int m = j - l1;
        if (m >= 0) f1v[j] = make_float2(cr[l1*11+m], ci[l1*11+m]);
        else { const int a2 = -m; const float sg = (a2&1)?-1.f:1.f;
               f1v[j] = make_float2(sg*cr[l1*11+a2], -sg*ci[l1*11+a2]); }
    }
    for (int j = 0; j <= 2*l2; ++j) {
        const int m = j - l2;
        if (m >= 0) f2v[j] = make_float2(cr[l2*11+m], ci[l2*11+m]);
        else { const int a2 = -m; const float sg = (a2&1)?-1.f:1.f;
               f2v[j] = make_float2(sg*cr[l2*11+a2], -sg*ci[l2*11+a2]); }
    }
    for (int j = 0; j <= 2*l; ++j) {
        const int m = j - l;
        if (m >= 0) flv[j] = make_float2(cr[l*11+m], ci[l*11+m]);
        else { const int a2 = -m; const float sg = (a2&1)?-1.f:1.f;
               flv[j] = make_float2(sg*cr[l*11+a2], -sg*ci[l*11+a2]); }
    }
    const float* cgp = cg + off + s;
    float r;
    switch (l) {
        case 0: r = core_fb<0>(f1v,f2v,flv,cgp,d1,d2,d); break;
        case 1: r = core_fb<1>(f1v,f2v,flv,cgp,d1,d2,d); break;
        case 2: r = core_fb<2>(f1v,f2v,flv,cgp,d1,d2,d); break;
        case 3: r = core_fb<3>(f1v,f2v,flv,cgp,d1,d2,d); break;
        case 4: r = core_fb<4>(f1v,f2v,flv,cgp,d1,d2,d); break;
        case 5: r = core_fb<5>(f1v,f2v,flv,cgp,d1,d2,d); break;
        case 6: r = core_fb<6>(f1v,f2v,flv,cgp,d1,d2,d); break;
        case 7: r = core_fb<7>(f1v,f2v,flv,cgp,d1,d2,d); break;
        case 8: r = core_fb<8>(f1v,f2v,flv,cgp,d1,d2,d); break;
        case 9: r = core_fb<9>(f1v,f2v,flv,cgp,d1,d2,d); break;
        default: r = core_fb<10>(f1v,f2v,flv,cgp,d1,d2,d); break;
    }
    out[(size_t)b * NCOLS + t] = r;
}

// ---------------------------------------------------------------------------
extern "C" void kernel_launch(void* const* d_in, const int* in_sizes, int n_in,
                              void* d_out, int out_size, void* d_ws, size_t ws_size,
                              hipStream_t stream)
{
    const float* cre = (const float*)d_in[0];
    const float* cim = (const float*)d_in[1];
    const float* cg  = (const float*)d_in[2];
    float* out = (float*)d_out;

    // compute cg16 total size (same walk as decode_pair_ext)
    long long c16_total = 0;
    for (int l1 = 0; l1 <= LMAX; ++l1)
        for (int l2 = l1; l2 <= LMAX; ++l2) {
            const int d    = (2*l1+1)*(2*l2+1);
            const int lmin = l2 - l1;
            const int lmx  = (l1 + l2 < LMAX) ? (l1 + l2) : LMAX;
            const int used = (lmx+1)*(lmx+1) - lmin*lmin;
            c16_total += (long long)((used+15)/16) * 16 * ((d+31)/32) * 32;
        }

    const size_t f_bytes = (size_t)NF * BATCH * sizeof(float2);   // 15,859,712
    const size_t need    = f_bytes + (size_t)c16_total * 2;       // ~17.8 MB

    if (ws_size >= need) {
        float2* f    = (float2*)d_ws;
        short*  cg16 = (short*)((char*)d_ws + f_bytes);
        build_f  <<<dim3(BATCH/256, NF),     256, 0, stream>>>(cre, cim, f);
        cg_to_f16<<<dim3(7, NPAIRS),         256, 0, stream>>>(cg, cg16);
        so3_mfma <<<dim3(BATCH/64, NPAIRS),  256, 0, stream>>>(f, cg16, out);
    } else {
        so3_tp_direct<<<dim3(BATCH/256, NCOLS), 256, 0, stream>>>(cre, cim, cg, out);
    }
}

// Round 12
// 363.871 us; speedup vs baseline: 1.2468x; 1.2468x over previous
//
#include <hip/hip_runtime.h>

#define LMAX   10
#define BATCH  16384
#define NCOLS  381
#define NF     121
#define NPAIRS 66

typedef __attribute__((ext_vector_type(8))) short    short8;
typedef __attribute__((ext_vector_type(8))) _Float16 half8;
typedef __attribute__((ext_vector_type(2))) _Float16 half2v;
typedef __attribute__((ext_vector_type(4))) float    floatx4;

__device__ __forceinline__ short f32_to_f16_bits(float x) {
    return __builtin_bit_cast(short, (_Float16)x);   // RNE
}

// pair index p -> (l1, l2, cg offset, first output column, cg16 offset)
__device__ __forceinline__ void decode_pair_ext(int p, int& l1, int& l2,
                                                long long& off, int& colbase,
                                                int& c16off)
{
    long long o = 0; int cb = 0, c16 = 0, idx = 0;
    for (int a = 0; a <= LMAX; ++a) {
        for (int bq = a; bq <= LMAX; ++bq) {
            const int d    = (2*a+1)*(2*bq+1);
            const int lmin = bq - a;
            const int lmx  = (a + bq < LMAX) ? (a + bq) : LMAX;
            const int used = (lmx+1)*(lmx+1) - lmin*lmin;
            const int npan = (d + 31) >> 5;
            const int nt   = (used + 15) >> 4;
            if (idx == p) { l1 = a; l2 = bq; off = o; colbase = cb; c16off = c16; return; }
            o += (long long)d * d; cb += lmx - lmin + 1;
            c16 += nt * 16 * npan * 32; ++idx;
        }
    }
    l1 = l2 = 0; off = 0; colbase = 0; c16off = 0;
}

// ---------------------------------------------------------------------------
// Kernel 1: expand coeffs into f planes, layout (121, BATCH) float2 (fp32).
// Verified (rounds 3/5/7/8/10).
// ---------------------------------------------------------------------------
__global__ __launch_bounds__(256) void build_f(const float* __restrict__ cre,
                                               const float* __restrict__ cim,
                                               float2* __restrict__ f)
{
    const int b   = blockIdx.x * blockDim.x + threadIdx.x;
    const int idx = blockIdx.y;                              // 0..120
    int l = (int)sqrtf((float)idx + 0.5f);
    if (l * l > idx) --l;
    if ((l + 1) * (l + 1) <= idx) ++l;
    const int j = idx - l * l;
    const int m = j - l;
    const float* crow  = cre + (size_t)b * 121 + l * 11;
    const float* cirow = cim + (size_t)b * 121 + l * 11;
    float re, im;
    if (m >= 0) { re = crow[m]; im = cirow[m]; }
    else {
        const int a = -m;
        const float sg = (a & 1) ? -1.0f : 1.0f;
        re = sg * crow[a]; im = -sg * cirow[a];
    }
    f[(size_t)idx * BATCH + b] = make_float2(re, im);
}

// ---------------------------------------------------------------------------
// Kernel 2: cg (fp32, [k][n] per pair) -> cg16 (f16, transposed [n][k],
// zero-padded to [nt*16][npan*32]). Verified (rounds 7/8/10).
// ---------------------------------------------------------------------------
__global__ __launch_bounds__(256) void cg_to_f16(const float* __restrict__ cg,
                                                 short* __restrict__ cg16)
{
    int l1, l2, colbase, c16off; long long off;
    decode_pair_ext(blockIdx.y, l1, l2, off, colbase, c16off);
    const int d    = (2*l1+1)*(2*l2+1);
    const int lmin = l2 - l1;
    const int lmx  = (l1 + l2 < LMAX) ? (l1 + l2) : LMAX;
    const int used = (lmx+1)*(lmx+1) - lmin*lmin;
    const int npan = (d + 31) >> 5;
    const int nt   = (used + 15) >> 4;
    const int K32  = npan * 32;
    const int kbase = blockIdx.x * 64;
    if (kbase >= K32) return;
    const int kend  = (kbase + 64 < K32) ? kbase + 64 : K32;
    const int usedp = nt * 16;
    const int nn = threadIdx.x & 127;
    const int kh = threadIdx.x >> 7;
    if (nn >= usedp) return;
    for (int k = kbase + kh; k < kend; k += 2) {
        float v = 0.f;
        if (nn < used && k < d)
            v = cg[off + (size_t)k * d + nn];
        cg16[(size_t)c16off + (size_t)nn * K32 + k] = f32_to_f16_bits(v);
    }
}

// ---------------------------------------------------------------------------
// MFMA pair kernel, hybrid (round 12 = round 11 + panel-0 commit fix):
//  - f1/f2 cached once in LDS (f12[m][65] packed half2).
//  - A fragments computed per-lane in registers (round 10, verified).
//  - B staged cooperatively into LDS, DOUBLE-BUFFERED, coalesced 16B chunks,
//    loaded once per block per panel; ONE __syncthreads per panel.
//  - T[64][123] epilogue with col<123 guard (round 10, verified).
// LDS: union{ f12 (10.93KB) + B0/B1 (2x10.24KB) = 31.4KB, T (31.49KB) }.
// ---------------------------------------------------------------------------
template<int NT>
__device__ __forceinline__ void pair_body(const float2* __restrict__ f,
                                          const short* __restrict__ cg16,
                                          float* __restrict__ out,
                                          short* smem, int btile,
                                          int l1, int l2, int c16off, int colbase)
{
    const int d1 = 2*l1 + 1, d2 = 2*l2 + 1, d = d1 * d2;
    const int lmin = l2 - l1;
    const int lmx  = (l1 + l2 < LMAX) ? (l1 + l2) : LMAX;
    const int n_l  = lmx - lmin + 1;
    const int q1 = l1*l1, q2 = l2*l2;
    const int npan = (d + 31) >> 5;
    const int K32  = npan * 32;

    const int tid  = threadIdx.x;
    const int lane = tid & 63;
    const int w    = tid >> 6;        // wave 0..3 -> M-tile
    const int quad = lane >> 4;
    const int r16  = lane & 15;

    unsigned int* f12 = (unsigned int*)smem;   // [m][65] packed half2 (<=10.92KB)
    short* B0 = smem + 5464;                   // [128][40] f16 bits (16B-aligned)
    short* B1 = B0 + 5120;

    // ---- load f1/f2 batch-tiles once, packed half2 {re, im} ----
    {
        const int nmm = (d1 + d2) * 64;
        for (int t2 = tid; t2 < nmm; t2 += 256) {
            const int m   = t2 >> 6;
            const int row = t2 & 63;
            const float2 v = (m < d1)
                ? f[(size_t)(q1 + m)      * BATCH + btile + row]
                : f[(size_t)(q2 + m - d1) * BATCH + btile + row];
            half2v h; h.x = (_Float16)v.x; h.y = (_Float16)v.y;
            f12[m * 65 + row] = __builtin_bit_cast(unsigned int, h);
        }
    }

    const short* cgbase = cg16 + (size_t)c16off;
    const int nchunk = NT * 64;                // 16B chunks per panel (<=512)

    // B prefetch: issue (global->regs) and commit (regs->LDS)
    short8 pf0, pf1;
    const int ch0 = tid, ch1 = tid + 256;
    const int n0c = ch0 >> 2, cc0 = (ch0 & 3) * 8;
    const int n1c = ch1 >> 2, cc1 = (ch1 & 3) * 8;

    // panel 0 into B0 (overlaps f12 staging above; barrier covers both)
    if (ch0 < nchunk) pf0 = *(const short8*)(cgbase + (size_t)n0c * K32 + cc0);
    if (ch1 < nchunk) pf1 = *(const short8*)(cgbase + (size_t)n1c * K32 + cc1);
    if (ch0 < nchunk) *(short8*)&B0[n0c * 40 + cc0] = pf0;
    if (ch1 < nchunk) *(short8*)&B0[n1c * 40 + cc1] = pf1;   // FIX: B0, not B1
    __syncthreads();

    floatx4 accR[NT], accI[NT];
#pragma unroll
    for (int i = 0; i < NT; ++i) {
        accR[i] = (floatx4)0.0f; accI[i] = (floatx4)0.0f;
    }

    const int row = w * 16 + r16;                 // this lane's batch row

    for (int pan = 0; pan < npan; ++pan) {
        const int k0 = pan << 5;
        short* Bc = (pan & 1) ? B1 : B0;
        short* Bn = (pan & 1) ? B0 : B1;

        // ---- issue next panel's global loads (no wait yet) ----
        const bool more = (pan + 1) < npan;
        if (more) {
            const int kn = (pan + 1) << 5;
            if (ch0 < nchunk) pf0 = *(const short8*)(cgbase + (size_t)n0c * K32 + kn + cc0);
            if (ch1 < nchunk) pf1 = *(const short8*)(cgbase + (size_t)n1c * K32 + kn + cc1);
        }

        // ---- A fragment in registers: tp[row][k0+quad*8 .. +7] (f16) ----
        int kk = k0 + quad * 8;
        int m1 = kk / d2;
        int m2 = kk - m1 * d2;
        short8 vr, vi;
#pragma unroll
        for (int j = 0; j < 8; ++j) {
            _Float16 tr = (_Float16)0.f, ti = (_Float16)0.f;
            if (kk < d) {
                const half2v a = __builtin_bit_cast(half2v, f12[m1 * 65 + row]);
                const half2v c = __builtin_bit_cast(half2v, f12[(d1 + m2) * 65 + row]);
                tr = a.x * c.x - a.y * c.y;
                ti = a.x * c.y + a.y * c.x;
            }
            vr[j] = __builtin_bit_cast(short, tr);
            vi[j] = __builtin_bit_cast(short, ti);
            ++kk;
            if (++m2 == d2) { m2 = 0; ++m1; }
        }
        const half8 are = __builtin_bit_cast(half8, vr);
        const half8 aim = __builtin_bit_cast(half8, vi);

        // ---- MFMA from current LDS buffer ----
#pragma unroll
        for (int n0 = 0; n0 < NT; ++n0) {
            const short8 b16 = *(const short8*)&Bc[(n0 * 16 + r16) * 40 + quad * 8];
            const half8 bb = __builtin_bit_cast(half8, b16);
            accR[n0] = __builtin_amdgcn_mfma_f32_16x16x32_f16(are, bb, accR[n0], 0, 0, 0);
            accI[n0] = __builtin_amdgcn_mfma_f32_16x16x32_f16(aim, bb, accI[n0], 0, 0, 0);
        }

        // ---- commit next panel to alternate buffer, one barrier ----
        if (more) {
            if (ch0 < nchunk) *(short8*)&Bn[n0c * 40 + cc0] = pf0;
            if (ch1 < nchunk) *(short8*)&Bn[n1c * 40 + cc1] = pf1;
        }
        __syncthreads();
    }

    // ---- two-pass fp32 epilogue; C/D: col=lane&15, row=quad*4+reg ----
    float* T = (float*)smem;                  // [64][123] fp32
    const int ntask = 64 * n_l;
    float part[3] = {0.f, 0.f, 0.f};

    // pass 1: real
#pragma unroll
    for (int n0 = 0; n0 < NT; ++n0)
#pragma unroll
        for (int r = 0; r < 4; ++r) {
            const int col = n0*16 + r16;
            if (col < 123)
                T[(w*16 + quad*4 + r) * 123 + col] = accR[n0][r];
        }
    __syncthreads();
    {
        int it = 0;
        for (int task = tid; task < ntask; task += 256, ++it) {
            const int trow = task & 63;
            const int li   = task >> 6;
            const int l    = lmin + li;
            const int sl   = l*l - lmin*lmin;
            const int W    = 2*l + 1;
            const int b    = btile + trow;
            const float* Trow = T + trow * 123 + sl;
            float acc = 0.f;
            for (int j = 0; j < W; ++j)
                acc = fmaf(Trow[j], f[(size_t)(l*l + j) * BATCH + b].x, acc);
            part[it] = acc;
        }
    }
    __syncthreads();

    // pass 2: imaginary
#pragma unroll
    for (int n0 = 0; n0 < NT; ++n0)
#pragma unroll
        for (int r = 0; r < 4; ++r) {
            const int col = n0*16 + r16;
            if (col < 123)
                T[(w*16 + quad*4 + r) * 123 + col] = accI[n0][r];
        }
    __syncthreads();
    {
        int it = 0;
        for (int task = tid; task < ntask; task += 256, ++it) {
            const int trow = task & 63;
            const int li   = task >> 6;
            const int l    = lmin + li;
            const int sl   = l*l - lmin*lmin;
            const int W    = 2*l + 1;
            const int b    = btile + trow;
            const float* Trow = T + trow * 123 + sl;
            float acc = part[it];
            for (int j = 0; j < W; ++j)
                acc = fmaf(Trow[j], f[(size_t)(l*l + j) * BATCH + b].y, acc);
            out[(size_t)b * NCOLS + colbase + li] = acc;
        }
    }
}

__global__ __launch_bounds__(256, 4) void so3_mfma(const float2* __restrict__ f,
                                                   const short* __restrict__ cg16,
                                                   float* __restrict__ out)
{
    __shared__ __align__(16) short smem[15744];   // 31.5 KB
    const int btile = blockIdx.x * 64;
    const int p     = blockIdx.y;
    int l1, l2, colbase, c16off; long long off;
    decode_pair_ext(p, l1, l2, off, colbase, c16off);
    const int lmin = l2 - l1;
    const int lmx  = (l1 + l2 < LMAX) ? (l1 + l2) : LMAX;
    const int used = (lmx+1)*(lmx+1) - lmin*lmin;
    const int nt   = (used + 15) >> 4;
    switch (nt) {
        case 1: pair_body<1>(f, cg16, out, smem, btile, l1, l2, c16off, colbase); break;
        case 2: pair_body<2>(f, cg16, out, smem, btile, l1, l2, c16off, colbase); break;
        case 3: pair_body<3>(f, cg16, out, smem, btile, l1, l2, c16off, colbase); break;
        case 4: pair_body<4>(f, cg16, out, smem, btile, l1, l2, c16off, colbase); break;
        case 5: pair_body<5>(f, cg16, out, smem, btile, l1, l2, c16off, colbase); break;
        case 6: pair_body<6>(f, cg16, out, smem, btile, l1, l2, c16off, colbase); break;
        case 7: pair_body<7>(f, cg16, out, smem, btile, l1, l2, c16off, colbase); break;
        default: pair_body<8>(f, cg16, out, smem, btile, l1, l2, c16off, colbase); break;
    }
}

// ---------------------------------------------------------------------------
// Full fallback (fp32 VALU, no workspace). Round-5 copy.
// ---------------------------------------------------------------------------
template<int L>
__device__ __forceinline__ float core_fb(const float2* f1v, const float2* f2v,
                                         const float2* flv,
                                         const float* __restrict__ cgp,
                                         int d1, int d2, int d)
{
    constexpr int W = 2*L + 1;
    float accr[W], acci[W];
#pragma unroll
    for (int k = 0; k < W; ++k) { accr[k] = 0.f; acci[k] = 0.f; }
    for (int m1 = 0; m1 < d1; ++m1) {
        const float2 a = f1v[m1];
        const float* rowbase = cgp + (size_t)m1 * d2 * d;
        for (int m2 = 0; m2 < d2; ++m2) {
            const float2 bb = f2v[m2];
            const float tr = a.x*bb.x - a.y*bb.y;
            const float ti = a.x*bb.y + a.y*bb.x;
            const float* row = rowbase + (size_t)m2 * d;
#pragma unroll
            for (int k = 0; k < W; ++k) {
                accr[k] = fmaf(tr, row[k], accr[k]);
                acci[k] = fmaf(ti, row[k], acci[k]);
            }
        }
    }
    float orr = 0.f;
#pragma unroll
    for (int k = 0; k < W; ++k)
        orr = fmaf(accr[k], flv[k].x, fmaf(acci[k], flv[k].y, orr));
    return orr;
}

__global__ __launch_bounds__(256) void so3_tp_direct(const float* __restrict__ cre,
                                                     const float* __restrict__ cim,
                                                     const float* __restrict__ cg,
                                                     float* __restrict__ out)
{
    const int b = blockIdx.x * blockDim.x + threadIdx.x;
    const int t = blockIdx.y;
    int l1 = 0, l2 = 0, l = 0; long long off = 0;
    {
        int tt = t; long long o = 0;
        bool found = false;
        for (int a = 0; a <= LMAX && !found; ++a)
            for (int bq = a; bq <= LMAX && !found; ++bq) {
                const int d = (2*a+1)*(2*bq+1);
                const int lmin = bq - a;
                const int lmx = (a+bq < LMAX) ? (a+bq) : LMAX;
                const int cnt = lmx - lmin + 1;
                if (tt < cnt) { l1 = a; l2 = bq; l = lmin + tt; off = o; found = true; }
                else { tt -= cnt; o += (long long)d*d; }
            }
    }
    const int d1 = 2*l1+1, d2 = 2*l2+1, d = d1*d2;
    const int lmin = l2 - l1;
    const int s = l*l - lmin*lmin;

    const float* cr = cre + (size_t)b * 121;
    const float* ci = cim + (size_t)b * 121;
    float2 f1v[21], f2v[21], flv[21];
    for (int j = 0; j <= 2*l1; ++j) {
        const int m = j - l1;
        if (m >= 0) f1v[j] = make_float2(cr[l1*11+m], ci[l1*11+m]);
        else { const int a2 = -m; const float sg = (a2&1)?-1.f:1.f;
               f1v[j] = make_float2(sg*cr[l1*11+a2], -sg*ci[l1*11+a2]); }
    }
    for (int j = 0; j <= 2*l2; ++j) {
        const int m = j - l2;
        if (m >= 0) f2v[j] = make_float2(cr[l2*11+m], ci[l2*11+m]);
        else { const int a2 = -m; const float sg = (a2&1)?-1.f:1.f;
               f2v[j] = make_float2(sg*cr[l2*11+a2], -sg*ci[l2*11+a2]); }
    }
    for (int j = 0; j <= 2*l; ++j) {
        const int m = j - l;
        if (m >= 0) flv[j] = make_float2(cr[l*11+m], ci[l*11+m]);
        else { const int a2 = -m; const float sg = (a2&1)?-1.f:1.f;
               flv[j] = make_float2(sg*cr[l*11+a2], -sg*ci[l*11+a2]); }
    }
    const float* cgp = cg + off + s;
    float r;
    switch (l) {
        case 0: r = core_fb<0>(f1v,f2v,flv,cgp,d1,d2,d); break;
        case 1: r = core_fb<1>(f1v,f2v,flv,cgp,d1,d2,d); break;
        case 2: r = core_fb<2>(f1v,f2v,flv,cgp,d1,d2,d); break;
        case 3: r = core_fb<3>(f1v,f2v,flv,cgp,d1,d2,d); break;
        case 4: r = core_fb<4>(f1v,f2v,flv,cgp,d1,d2,d); break;
        case 5: r = core_fb<5>(f1v,f2v,flv,cgp,d1,d2,d); break;
        case 6: r = core_fb<6>(f1v,f2v,flv,cgp,d1,d2,d); break;
        case 7: r = core_fb<7>(f1v,f2v,flv,cgp,d1,d2,d); break;
        case 8: r = core_fb<8>(f1v,f2v,flv,cgp,d1,d2,d); break;
        case 9: r = core_fb<9>(f1v,f2v,flv,cgp,d1,d2,d); break;
        default: r = core_fb<10>(f1v,f2v,flv,cgp,d1,d2,d); break;
    }
    out[(size_t)b * NCOLS + t] = r;
}

// ---------------------------------------------------------------------------
extern "C" void kernel_launch(void* const* d_in, const int* in_sizes, int n_in,
                              void* d_out, int out_size, void* d_ws, size_t ws_size,
                              hipStream_t stream)
{
    const float* cre = (const float*)d_in[0];
    const float* cim = (const float*)d_in[1];
    const float* cg  = (const float*)d_in[2];
    float* out = (float*)d_out;

    // compute cg16 total size (same walk as decode_pair_ext)
    long long c16_total = 0;
    for (int l1 = 0; l1 <= LMAX; ++l1)
        for (int l2 = l1; l2 <= LMAX; ++l2) {
            const int d    = (2*l1+1)*(2*l2+1);
            const int lmin = l2 - l1;
            const int lmx  = (l1 + l2 < LMAX) ? (l1 + l2) : LMAX;
            const int used = (lmx+1)*(lmx+1) - lmin*lmin;
            c16_total += (long long)((used+15)/16) * 16 * ((d+31)/32) * 32;
        }

    const size_t f_bytes = (size_t)NF * BATCH * sizeof(float2);   // 15,859,712
    const size_t need    = f_bytes + (size_t)c16_total * 2;       // ~17.8 MB

    if (ws_size >= need) {
        float2* f    = (float2*)d_ws;
        short*  cg16 = (short*)((char*)d_ws + f_bytes);
        build_f  <<<dim3(BATCH/256, NF),     256, 0, stream>>>(cre, cim, f);
        cg_to_f16<<<dim3(7, NPAIRS),         256, 0, stream>>>(cg, cg16);
        so3_mfma <<<dim3(BATCH/64, NPAIRS),  256, 0, stream>>>(f, cg16, out);
    } else {
        so3_tp_direct<<<dim3(BATCH/256, NCOLS), 256, 0, stream>>>(cre, cim, cg, out);
    }
}